// Round 7
// baseline (24.707 us; speedup 1.0000x reference)
//
#include <hip/hip_runtime.h>

// Problem constants: B,D,K,CI,CO,L,NB,P,S = 4,32,8,2,2,4096,15,7,8
constexpr int Bc  = 4;
constexpr int Dc  = 32;
constexpr int Kc  = 8;
constexpr int CIc = 2;
constexpr int COc = 2;
constexpr int Lc  = 4096;
constexpr int NBc = 15;
constexpr int Sc  = 8;

constexpr int NTHREADS = 256;
constexpr int JT       = 8;                  // outputs per thread per co
constexpr int TILE     = NTHREADS * JT;      // 2048 l per block
constexpr int XROW     = TILE + 16;          // staged row: [lbase-8, lbase+TILE+8)
constexpr int WELEMS   = COc * CIc * Sc * NBc;  // 480
constexpr int WIN      = JT + 16;            // 24-float x window per ci

typedef float f32x4 __attribute__((ext_vector_type(4)));

// seg(l) = min(l/499, 7)
__device__ __forceinline__ int seg_of(int l) {
    int s = l / 499;
    return s > 7 ? 7 : s;
}

__global__ __launch_bounds__(NTHREADS) void cde_bcr_kernel(
    const float* __restrict__ x,     // [B][D][K][CI][L]
    const float* __restrict__ w,     // [D][K][CO][CI][S][1][NB]
    const float* __restrict__ bias,  // [D][K][CO][S][1]
    float* __restrict__ out)         // [B][D][K][CO][L]
{
    // x staged in LDS: global loads perfectly coalesced (16B lane stride),
    // window reads are ds_read_b128 at 32B lane stride = 2-way conflict (free, m136).
    __shared__ __align__(16) float xs[CIc][XROW];
    __shared__ __align__(16) float wl[COc * CIc * Sc][16]; // row=(o*CI+i)*S+s
    __shared__ float bl[COc * Sc];

    const int tid   = threadIdx.x;
    const int lbase = blockIdx.x * TILE;
    const int bdk   = blockIdx.y;            // ((b*D + d)*K + k)
    const int dk    = bdk % (Dc * Kc);

    // ---- weights + bias ----
    for (int t = tid; t < WELEMS; t += NTHREADS)
        wl[t / NBc][t % NBc] = w[(size_t)dk * WELEMS + t];
    if (tid < COc * Sc)
        bl[tid] = bias[(size_t)dk * (COc * Sc) + tid];

    // ---- stage x: interior, 2 float4 sweeps per ci, lane-contiguous ----
    const float* xb = x + (size_t)bdk * CIc * Lc;
#pragma unroll
    for (int i = 0; i < CIc; ++i) {
#pragma unroll
        for (int q = 0; q < TILE / (NTHREADS * 4); ++q) {   // 2 sweeps
            int off = q * NTHREADS * 4 + tid * 4;
            f32x4 v = *(const f32x4*)(xb + (size_t)i * Lc + lbase + off);
            *(f32x4*)&xs[i][8 + off] = v;
        }
    }
    // halos: left m in [0,8) <- l in [lbase-8, lbase); right m in [8+TILE, 16+TILE)
    if (tid < 2 * CIc * 8) {
        int which = tid / (CIc * 8);
        int rem   = tid % (CIc * 8);
        int i = rem / 8, e = rem % 8;
        int m = which ? (8 + TILE + e) : e;
        int l = lbase + (which ? (TILE + e) : (e - 8));
        xs[i][m] = (l >= 0 && l < Lc) ? xb[(size_t)i * Lc + l] : 0.0f;
    }
    __syncthreads();

    const int l0  = tid * JT;
    const int gl0 = lbase + l0;
    const int s0  = seg_of(gl0);
    const int s7  = seg_of(gl0 + JT - 1);

    // ---- windows from LDS: xa_i[m] = x[i][gl0-8+m] = xs[i][l0+m], m in [0,24) ----
    float xa0[WIN], xa1[WIN];
#pragma unroll
    for (int m = 0; m < WIN / 4; ++m)
        *(f32x4*)&xa0[4 * m] = *(const f32x4*)&xs[0][l0 + 4 * m];
#pragma unroll
    for (int m = 0; m < WIN / 4; ++m)
        *(f32x4*)&xa1[4 * m] = *(const f32x4*)&xs[1][l0 + 4 * m];

    float acc[COc][JT];
#pragma unroll
    for (int o = 0; o < COc; ++o)
#pragma unroll
        for (int j = 0; j < JT; ++j)
            acc[o][j] = bl[o * Sc + s0];

    // ---- main FMA block, uniform segment s0 ----
#pragma unroll
    for (int i = 0; i < CIc; ++i) {
        float w0[16], w1[16];
#pragma unroll
        for (int m = 0; m < 4; ++m) {
            *(f32x4*)&w0[4 * m] = *(const f32x4*)&wl[(0 * CIc + i) * Sc + s0][4 * m];
            *(f32x4*)&w1[4 * m] = *(const f32x4*)&wl[(1 * CIc + i) * Sc + s0][4 * m];
        }
#pragma unroll
        for (int f = 0; f < NBc; ++f) {
#pragma unroll
            for (int j = 0; j < JT; ++j) {
                float xv = (i == 0) ? xa0[j + f + 1] : xa1[j + f + 1];
                acc[0][j] = fmaf(w0[f], xv, acc[0][j]);
                acc[1][j] = fmaf(w1[f], xv, acc[1][j]);
            }
        }
    }

    // ---- fixup: segment-boundary threads (<=7 per bdk row), all indices static ----
    if (s7 != s0) {
        const int jstart = 499 * s7 - gl0;   // in [1, JT-1]
        const float b0 = bl[0 * Sc + s7];
        const float b1 = bl[1 * Sc + s7];
#pragma unroll
        for (int j = 0; j < JT; ++j) {
            if (j >= jstart) {
                float a0 = b0, a1 = b1;
#pragma unroll
                for (int i = 0; i < CIc; ++i) {
#pragma unroll
                    for (int f = 0; f < NBc; ++f) {
                        float xv = (i == 0) ? xa0[j + f + 1] : xa1[j + f + 1];
                        a0 = fmaf(wl[(0 * CIc + i) * Sc + s7][f], xv, a0);
                        a1 = fmaf(wl[(1 * CIc + i) * Sc + s7][f], xv, a1);
                    }
                }
                acc[0][j] = a0;
                acc[1][j] = a1;
            }
        }
    }

    // ---- store: 4 nontemporal dwordx4 ----
    float* ob = out + (size_t)bdk * COc * Lc + gl0;
#pragma unroll
    for (int o = 0; o < COc; ++o) {
        f32x4 v0 = { acc[o][0], acc[o][1], acc[o][2], acc[o][3] };
        f32x4 v1 = { acc[o][4], acc[o][5], acc[o][6], acc[o][7] };
        __builtin_nontemporal_store(v0, (f32x4*)(ob + (size_t)o * Lc));
        __builtin_nontemporal_store(v1, (f32x4*)(ob + (size_t)o * Lc + 4));
    }
}

extern "C" void kernel_launch(void* const* d_in, const int* in_sizes, int n_in,
                              void* d_out, int out_size, void* d_ws, size_t ws_size,
                              hipStream_t stream) {
    const float* x    = (const float*)d_in[0];
    const float* w    = (const float*)d_in[1];
    const float* bias = (const float*)d_in[2];
    float* out        = (float*)d_out;

    dim3 grid(Lc / TILE, Bc * Dc * Kc);   // 2 x 1024 blocks
    cde_bcr_kernel<<<grid, NTHREADS, 0, stream>>>(x, w, bias, out);
}

// Round 8
// 24.095 us; speedup vs baseline: 1.0254x; 1.0254x over previous
//
#include <hip/hip_runtime.h>

// Problem constants: B,D,K,CI,CO,L,NB,P,S = 4,32,8,2,2,4096,15,7,8
constexpr int Bc  = 4;
constexpr int Dc  = 32;
constexpr int Kc  = 8;
constexpr int CIc = 2;
constexpr int COc = 2;
constexpr int Lc  = 4096;
constexpr int NBc = 15;
constexpr int Sc  = 8;

constexpr int NTHREADS = 256;
constexpr int JT       = 8;                  // outputs per thread per co
constexpr int TILE     = NTHREADS * JT;      // 2048 l per block
constexpr int WELEMS   = COc * CIc * Sc * NBc;  // 480

typedef float f32x4 __attribute__((ext_vector_type(4)));

// window accessor: xa[m] = x[gl0 - 8 + m], m in [0,24), from {left, own, right} regs.
// m is always a compile-time constant after unrolling -> pure register indexing.
#define XA(i, m) ((m) < 8 ? (i ? lf1[(m)] : lf0[(m)]) \
                 : (m) < 16 ? (i ? own1[(m)-8] : own0[(m)-8]) \
                 : (i ? rt1[(m)-16] : rt0[(m)-16]))

// seg(l) = min(l/499, 7)
__device__ __forceinline__ int seg_of(int l) {
    int s = l / 499;
    return s > 7 ? 7 : s;
}

__global__ __launch_bounds__(NTHREADS) void cde_bcr_kernel(
    const float* __restrict__ x,     // [B][D][K][CI][L]
    const float* __restrict__ w,     // [D][K][CO][CI][S][1][NB]
    const float* __restrict__ bias,  // [D][K][CO][S][1]
    float* __restrict__ out)         // [B][D][K][CO][L]
{
    __shared__ __align__(16) float wl[COc * CIc * Sc][16]; // row=(o*CI+i)*S+s
    __shared__ float bl[COc * Sc];

    const int tid   = threadIdx.x;
    const int lane  = tid & 63;
    const int lbase = blockIdx.x * TILE;
    const int bdk   = blockIdx.y;            // ((b*D + d)*K + k)
    const int dk    = bdk % (Dc * Kc);

    for (int t = tid; t < WELEMS; t += NTHREADS)
        wl[t / NBc][t % NBc] = w[(size_t)dk * WELEMS + t];
    if (tid < COc * Sc)
        bl[tid] = bias[(size_t)dk * (COc * Sc) + tid];
    __syncthreads();

    const int l0  = tid * JT;
    const int gl0 = lbase + l0;
    const int s0  = seg_of(gl0);
    const int s7  = seg_of(gl0 + JT - 1);

    const float* xb  = x + (size_t)bdk * CIc * Lc;
    const float* xi0 = xb + gl0;
    const float* xi1 = xb + Lc + gl0;

    // ---- own 8 floats per ci: wave reads a CONTIGUOUS 2KB block (optimal coalescing) ----
    float own0[8], own1[8];
    *(f32x4*)&own0[0] = *(const f32x4*)(xi0);
    *(f32x4*)&own0[4] = *(const f32x4*)(xi0 + 4);
    *(f32x4*)&own1[0] = *(const f32x4*)(xi1);
    *(f32x4*)&own1[4] = *(const f32x4*)(xi1 + 4);

    // ---- halos from neighbor lanes via shuffle (no LDS traffic for x, no barrier) ----
    float lf0[8], lf1[8], rt0[8], rt1[8];
#pragma unroll
    for (int m = 0; m < 8; ++m) {
        lf0[m] = __shfl_up(own0[m], 1);
        lf1[m] = __shfl_up(own1[m], 1);
        rt0[m] = __shfl_down(own0[m], 1);
        rt1[m] = __shfl_down(own1[m], 1);
    }
    // wave-edge lanes: fetch halo from global (exec-masked to 2 lanes/wave), bounds-checked
    if (lane == 0) {
        if (gl0 >= 8) {
            *(f32x4*)&lf0[0] = *(const f32x4*)(xi0 - 8);
            *(f32x4*)&lf0[4] = *(const f32x4*)(xi0 - 4);
            *(f32x4*)&lf1[0] = *(const f32x4*)(xi1 - 8);
            *(f32x4*)&lf1[4] = *(const f32x4*)(xi1 - 4);
        } else {
#pragma unroll
            for (int m = 0; m < 8; ++m) { lf0[m] = 0.0f; lf1[m] = 0.0f; }
        }
    }
    if (lane == 63) {
        if (gl0 + 16 <= Lc) {
            *(f32x4*)&rt0[0] = *(const f32x4*)(xi0 + 8);
            *(f32x4*)&rt0[4] = *(const f32x4*)(xi0 + 12);
            *(f32x4*)&rt1[0] = *(const f32x4*)(xi1 + 8);
            *(f32x4*)&rt1[4] = *(const f32x4*)(xi1 + 12);
        } else {
#pragma unroll
            for (int m = 0; m < 8; ++m) { rt0[m] = 0.0f; rt1[m] = 0.0f; }
        }
    }

    float acc[COc][JT];
#pragma unroll
    for (int o = 0; o < COc; ++o)
#pragma unroll
        for (int j = 0; j < JT; ++j)
            acc[o][j] = bl[o * Sc + s0];

    // ---- main FMA block, uniform segment s0 ----
#pragma unroll
    for (int i = 0; i < CIc; ++i) {
        float w0[16], w1[16];
#pragma unroll
        for (int m = 0; m < 4; ++m) {
            *(f32x4*)&w0[4 * m] = *(const f32x4*)&wl[(0 * CIc + i) * Sc + s0][4 * m];
            *(f32x4*)&w1[4 * m] = *(const f32x4*)&wl[(1 * CIc + i) * Sc + s0][4 * m];
        }
#pragma unroll
        for (int f = 0; f < NBc; ++f) {
#pragma unroll
            for (int j = 0; j < JT; ++j) {
                float xv = XA(i, j + f + 1);
                acc[0][j] = fmaf(w0[f], xv, acc[0][j]);
                acc[1][j] = fmaf(w1[f], xv, acc[1][j]);
            }
        }
    }

    // ---- fixup: segment-boundary threads (<=7 per bdk row), all indices static ----
    if (s7 != s0) {
        const int jstart = 499 * s7 - gl0;   // in [1, JT-1]
        const float b0 = bl[0 * Sc + s7];
        const float b1 = bl[1 * Sc + s7];
#pragma unroll
        for (int j = 0; j < JT; ++j) {
            if (j >= jstart) {
                float a0 = b0, a1 = b1;
#pragma unroll
                for (int i = 0; i < CIc; ++i) {
#pragma unroll
                    for (int f = 0; f < NBc; ++f) {
                        float xv = XA(i, j + f + 1);
                        a0 = fmaf(wl[(0 * CIc + i) * Sc + s7][f], xv, a0);
                        a1 = fmaf(wl[(1 * CIc + i) * Sc + s7][f], xv, a1);
                    }
                }
                acc[0][j] = a0;
                acc[1][j] = a1;
            }
        }
    }

    // ---- store: 4 nontemporal dwordx4, pairwise contiguous ----
    float* ob = out + (size_t)bdk * COc * Lc + gl0;
#pragma unroll
    for (int o = 0; o < COc; ++o) {
        f32x4 v0 = { acc[o][0], acc[o][1], acc[o][2], acc[o][3] };
        f32x4 v1 = { acc[o][4], acc[o][5], acc[o][6], acc[o][7] };
        __builtin_nontemporal_store(v0, (f32x4*)(ob + (size_t)o * Lc));
        __builtin_nontemporal_store(v1, (f32x4*)(ob + (size_t)o * Lc + 4));
    }
}

extern "C" void kernel_launch(void* const* d_in, const int* in_sizes, int n_in,
                              void* d_out, int out_size, void* d_ws, size_t ws_size,
                              hipStream_t stream) {
    const float* x    = (const float*)d_in[0];
    const float* w    = (const float*)d_in[1];
    const float* bias = (const float*)d_in[2];
    float* out        = (float*)d_out;

    dim3 grid(Lc / TILE, Bc * Dc * Kc);   // 2 x 1024 blocks
    cde_bcr_kernel<<<grid, NTHREADS, 0, stream>>>(x, w, bias, out);
}